// Round 3
// baseline (180.066 us; speedup 1.0000x reference)
//
#include <hip/hip_runtime.h>
#include <math.h>

#define HW1 (1024 * 1024)
#define WID 1024
#define HEI 1024

// Block-level reduce (wave shfl + LDS) then one atomicAdd per block.
__device__ __forceinline__ void block_atomic_add(float v, float* target, volatile float* sdata) {
#pragma unroll
    for (int off = 32; off > 0; off >>= 1)
        v += __shfl_down(v, off, 64);
    const int lane = threadIdx.x & 63;
    const int wv   = threadIdx.x >> 6;
    if (lane == 0) sdata[wv] = v;
    __syncthreads();
    if (threadIdx.x == 0) {
        float s = 0.f;
        const int nw = blockDim.x >> 6;
        for (int i = 0; i < nw; ++i) s += sdata[i];
        atomicAdd(target, s);
    }
    __syncthreads();
}

// Fused kernel. Blocks [0,1024): main pass (r_loss, c_loss, pooled diff).
// Blocks [1024,1792): Sobel s_loss on batch-0 planes.
__global__ __launch_bounds__(256, 4) void k_fused(const float* __restrict__ A,
                                                  const float* __restrict__ B,
                                                  float* __restrict__ pool,
                                                  float* __restrict__ acc) {
    __shared__ float pd_lds[24 * 4 * 64];   // main path: [plane][yl][xl]
    __shared__ float s1[4], s2[4];

    const int tid = threadIdx.x;

    if (blockIdx.x < 1024) {
        // ---------------- main path: one thread owns a 4x1 row strip ----------------
        const int xl    = tid & 63;
        const int yl    = tid >> 6;
        const int gy    = blockIdx.x >> 2;
        const int chunk = blockIdx.x & 3;
        const int gx    = chunk * 64 + xl;
        const int px    = gx * 4;
        const int y     = gy * 4 + yl;
        const size_t rowoff = (size_t)y * WID + px;

        float na2[12], nb2[12], dt[12];
#pragma unroll
        for (int i = 0; i < 12; ++i) { na2[i] = 0.f; nb2[i] = 0.f; dt[i] = 0.f; }
        float r_sum = 0.f;

#pragma unroll
        for (int c = 0; c < 3; ++c) {
            // Issue all 16 loads for this channel (8 batches x {A,B}) before consuming:
            // maximizes memory-level parallelism per wave.
            float4 av[8], bv[8];
#pragma unroll
            for (int b = 0; b < 8; ++b) {
                const size_t poff = (size_t)(b * 3 + c) * HW1 + rowoff;
                av[b] = *reinterpret_cast<const float4*>(A + poff);
                bv[b] = *reinterpret_cast<const float4*>(B + poff);
            }
#pragma unroll
            for (int b = 0; b < 8; ++b) {
                float pd = 0.f;
                {
                    float a = av[b].x, t = bv[b].x;
                    na2[c * 4 + 0] += a * a; nb2[c * 4 + 0] += t * t; dt[c * 4 + 0] += a * t;
                    r_sum += fabsf(a - t); pd += t - a;
                }
                {
                    float a = av[b].y, t = bv[b].y;
                    na2[c * 4 + 1] += a * a; nb2[c * 4 + 1] += t * t; dt[c * 4 + 1] += a * t;
                    r_sum += fabsf(a - t); pd += t - a;
                }
                {
                    float a = av[b].z, t = bv[b].z;
                    na2[c * 4 + 2] += a * a; nb2[c * 4 + 2] += t * t; dt[c * 4 + 2] += a * t;
                    r_sum += fabsf(a - t); pd += t - a;
                }
                {
                    float a = av[b].w, t = bv[b].w;
                    na2[c * 4 + 3] += a * a; nb2[c * 4 + 3] += t * t; dt[c * 4 + 3] += a * t;
                    r_sum += fabsf(a - t); pd += t - a;
                }
                pd_lds[((b * 3 + c) * 4 + yl) * 64 + xl] = pd;
            }
        }
        __syncthreads();

        // y-reduce pooled diff and write pool
#pragma unroll
        for (int idx = tid; idx < 24 * 64; idx += 256) {
            const int plane = idx >> 6;
            const int x     = idx & 63;
            const float s = pd_lds[(plane * 4 + 0) * 64 + x] + pd_lds[(plane * 4 + 1) * 64 + x]
                          + pd_lds[(plane * 4 + 2) * 64 + x] + pd_lds[(plane * 4 + 3) * 64 + x];
            pool[(size_t)plane * 65536 + gy * 256 + chunk * 64 + x] = s * (1.0f / 16.0f);
        }

        float c_sum = 0.f;
#pragma unroll
        for (int xi = 0; xi < 4; ++xi) {
            float cs = 0.f;
#pragma unroll
            for (int c = 0; c < 3; ++c) {
                float na = fmaxf(sqrtf(na2[c * 4 + xi]), 1e-12f);
                float nb = fmaxf(sqrtf(nb2[c * 4 + xi]), 1e-12f);
                cs += dt[c * 4 + xi] / (na * nb);
            }
            cs = fminf(fmaxf(cs, -1.0f + 1e-7f), 1.0f - 1e-7f);
            c_sum += acosf(cs);
        }

        block_atomic_add(r_sum, acc + 0, s1);
        block_atomic_add(c_sum, acc + 1, s2);
    } else {
        // ---------------- Sobel path: 4x4 output tile per thread ----------------
        const int t   = (blockIdx.x - 1024) * 256 + tid;  // 0 .. 196607
        const int qx  = t & 255;          // x strip
        const int rem = t >> 8;           // 0..767
        const int qy  = rem & 255;        // y strip
        const int c   = rem >> 8;         // 0..2
        const int x0  = qx * 4;
        const int y0  = qy * 4;

        const float* Ap = A + (size_t)c * HW1;
        const float* Bp = B + (size_t)c * HW1;

        // rowdiff(y,x) = d(y,x-1) - d(y,x+1), rows y0-1 .. y0+4
        float rd[6][4];
#pragma unroll
        for (int r = 0; r < 6; ++r) {
            const int yy = y0 - 1 + r;
            if (yy < 0 || yy >= HEI) {
                rd[r][0] = rd[r][1] = rd[r][2] = rd[r][3] = 0.f;
                continue;
            }
            const float* ap = Ap + (size_t)yy * WID;
            const float* bp = Bp + (size_t)yy * WID;
            const float4 a4 = *reinterpret_cast<const float4*>(ap + x0);
            const float4 b4 = *reinterpret_cast<const float4*>(bp + x0);
            const float dm = (qx > 0)   ? (ap[x0 - 1] - bp[x0 - 1]) : 0.f;
            const float dp = (qx < 255) ? (ap[x0 + 4] - bp[x0 + 4]) : 0.f;
            const float d0 = a4.x - b4.x;
            const float d1 = a4.y - b4.y;
            const float d2 = a4.z - b4.z;
            const float d3 = a4.w - b4.w;
            rd[r][0] = dm - d1;
            rd[r][1] = d0 - d2;
            rd[r][2] = d1 - d3;
            rd[r][3] = d2 - dp;
        }

        float s = 0.f;
#pragma unroll
        for (int o = 0; o < 4; ++o) {
#pragma unroll
            for (int i = 0; i < 4; ++i)
                s += fabsf(rd[o][i] + 2.f * rd[o + 1][i] + rd[o + 2][i]);
        }

        block_atomic_add(s, acc + 2, s1);
    }
}

// Spatial-consistency loss from pooled diff array P[24][256][256].
__global__ __launch_bounds__(256) void k_spa(const float* __restrict__ P,
                                             float* __restrict__ acc) {
    const int t = blockIdx.x * 256 + threadIdx.x;  // 0 .. 524287
    const int x = t & 255;
    const int y = (t >> 8) & 255;
    const int b = t >> 16;  // 0..7

    const float* Rr = P + (size_t)(b * 3 + 0) * 65536 + y * 256;
    const float* Gg = P + (size_t)(b * 3 + 1) * 65536 + y * 256;
    const float* Bb = P + (size_t)(b * 3 + 2) * 65536 + y * 256;

    const float g  = Gg[x];
    const float gl = (x > 0)   ? Gg[x - 1] : 0.f;
    const float gr = (x < 255) ? Gg[x + 1] : 0.f;
    const float d0 = g - gl;
    const float d1 = g - gr;
    const float d2 = g - Rr[x];
    const float d3 = g - Bb[x];
    float s = d0 * d0 + d1 * d1 + d2 * d2 + d3 * d3;

    __shared__ float sd[4];
    block_atomic_add(s, acc + 3, sd);
}

// Combine: out = W_C*c + W_R*r + W_P*p + W_S*s
__global__ void k_final(const float* __restrict__ acc, float* __restrict__ out) {
    const float r = acc[0] * (1.0f / 25165824.0f);  // mean over 8*3*1024*1024
    const float c = acc[1];
    const float s = acc[2];
    const float p = acc[3] * (1.0f / 524288.0f);    // mean over 8*256*256
    out[0] = 0.5f * c + 1.0f * r + 1.0f * p + 0.1f * s;
}

extern "C" void kernel_launch(void* const* d_in, const int* in_sizes, int n_in,
                              void* d_out, int out_size, void* d_ws, size_t ws_size,
                              hipStream_t stream) {
    const float* A = (const float*)d_in[0];  // predictions
    const float* B = (const float*)d_in[1];  // targets
    float* acc  = (float*)d_ws;              // 4 accumulators (+ padding)
    float* pool = (float*)d_ws + 64;         // 8*3*256*256 floats = 6.29 MB

    hipMemsetAsync(d_ws, 0, 64 * sizeof(float), stream);

    hipLaunchKernelGGL(k_fused, dim3(1792), dim3(256), 0, stream, A, B, pool, acc);
    hipLaunchKernelGGL(k_spa,   dim3(2048), dim3(256), 0, stream, pool, acc);
    hipLaunchKernelGGL(k_final, dim3(1),    dim3(1),   0, stream, acc, (float*)d_out);
}

// Round 4
// 102.941 us; speedup vs baseline: 1.7492x; 1.7492x over previous
//
#include <hip/hip_runtime.h>
#include <math.h>

#define HW1 (1024 * 1024)
#define WID 1024
#define HEI 1024

// Block-level reduce (wave shfl + LDS) then one atomicAdd per block.
__device__ __forceinline__ void block_atomic_add(float v, float* target, volatile float* sdata) {
#pragma unroll
    for (int off = 32; off > 0; off >>= 1)
        v += __shfl_down(v, off, 64);
    const int lane = threadIdx.x & 63;
    const int wv   = threadIdx.x >> 6;
    if (lane == 0) sdata[wv] = v;
    __syncthreads();
    if (threadIdx.x == 0) {
        float s = 0.f;
        const int nw = blockDim.x >> 6;
        for (int i = 0; i < nw; ++i) s += sdata[i];
        atomicAdd(target, s);
    }
    __syncthreads();
}

// Fused kernel. Blocks [0,1024): main pass (r_loss, c_loss, pooled diff).
// Blocks [1024,1792): Sobel s_loss on batch-0 planes.
// NOTE: no min-waves clamp — the 16 staged float4 loads need ~64 VGPRs of
// data; clamping to 4 waves/EU (round 3) forced a scratch spill (WRITE_SIZE
// 6 MB -> 225 MB). Let the allocator pick ~130 VGPR -> 4 waves/EU naturally.
__global__ __launch_bounds__(256) void k_fused(const float* __restrict__ A,
                                               const float* __restrict__ B,
                                               float* __restrict__ pool,
                                               float* __restrict__ acc) {
    __shared__ float pd_lds[24 * 4 * 64];   // main path: [plane][yl][xl]
    __shared__ float s1[4], s2[4];

    const int tid = threadIdx.x;

    if (blockIdx.x < 1024) {
        // ---------------- main path: one thread owns a 4x1 row strip ----------------
        const int xl    = tid & 63;
        const int yl    = tid >> 6;
        const int gy    = blockIdx.x >> 2;
        const int chunk = blockIdx.x & 3;
        const int Q     = chunk * 64 + xl;     // pool-x 0..255 (= float4 index in row)
        const int y     = gy * 4 + yl;
        const int rowq  = y * 256 + Q;         // float4 index within a plane

        const float4* A4 = reinterpret_cast<const float4*>(A);
        const float4* B4 = reinterpret_cast<const float4*>(B);

        float na2[12], nb2[12], dt[12];
#pragma unroll
        for (int i = 0; i < 12; ++i) { na2[i] = 0.f; nb2[i] = 0.f; dt[i] = 0.f; }
        float r_sum = 0.f;

#pragma unroll
        for (int c = 0; c < 3; ++c) {
            // Issue all 16 loads for this channel (8 batches x {A,B}) before
            // consuming: 16 KB in flight per wave.
            float4 av[8], bv[8];
#pragma unroll
            for (int b = 0; b < 8; ++b) {
                const int p4 = (b * 3 + c) * (HW1 / 4) + rowq;
                av[b] = A4[p4];
                bv[b] = B4[p4];
            }
#pragma unroll
            for (int b = 0; b < 8; ++b) {
                float pd = 0.f;
                {
                    float a = av[b].x, t = bv[b].x;
                    na2[c * 4 + 0] += a * a; nb2[c * 4 + 0] += t * t; dt[c * 4 + 0] += a * t;
                    r_sum += fabsf(a - t); pd += t - a;
                }
                {
                    float a = av[b].y, t = bv[b].y;
                    na2[c * 4 + 1] += a * a; nb2[c * 4 + 1] += t * t; dt[c * 4 + 1] += a * t;
                    r_sum += fabsf(a - t); pd += t - a;
                }
                {
                    float a = av[b].z, t = bv[b].z;
                    na2[c * 4 + 2] += a * a; nb2[c * 4 + 2] += t * t; dt[c * 4 + 2] += a * t;
                    r_sum += fabsf(a - t); pd += t - a;
                }
                {
                    float a = av[b].w, t = bv[b].w;
                    na2[c * 4 + 3] += a * a; nb2[c * 4 + 3] += t * t; dt[c * 4 + 3] += a * t;
                    r_sum += fabsf(a - t); pd += t - a;
                }
                pd_lds[((b * 3 + c) * 4 + yl) * 64 + xl] = pd;
            }
        }
        __syncthreads();

        // y-reduce pooled diff and write pool
#pragma unroll
        for (int idx = tid; idx < 24 * 64; idx += 256) {
            const int plane = idx >> 6;
            const int x     = idx & 63;
            const float s = pd_lds[(plane * 4 + 0) * 64 + x] + pd_lds[(plane * 4 + 1) * 64 + x]
                          + pd_lds[(plane * 4 + 2) * 64 + x] + pd_lds[(plane * 4 + 3) * 64 + x];
            pool[(size_t)plane * 65536 + gy * 256 + chunk * 64 + x] = s * (1.0f / 16.0f);
        }

        float c_sum = 0.f;
#pragma unroll
        for (int xi = 0; xi < 4; ++xi) {
            float cs = 0.f;
#pragma unroll
            for (int c = 0; c < 3; ++c) {
                float na = fmaxf(sqrtf(na2[c * 4 + xi]), 1e-12f);
                float nb = fmaxf(sqrtf(nb2[c * 4 + xi]), 1e-12f);
                cs += dt[c * 4 + xi] / (na * nb);
            }
            cs = fminf(fmaxf(cs, -1.0f + 1e-7f), 1.0f - 1e-7f);
            c_sum += acosf(cs);
        }

        block_atomic_add(r_sum, acc + 0, s1);
        block_atomic_add(c_sum, acc + 1, s2);
    } else {
        // ---------------- Sobel path: 4x4 output tile per thread ----------------
        const int t   = (blockIdx.x - 1024) * 256 + tid;  // 0 .. 196607
        const int qx  = t & 255;          // x strip
        const int rem = t >> 8;           // 0..767
        const int qy  = rem & 255;        // y strip
        const int c   = rem >> 8;         // 0..2
        const int x0  = qx * 4;
        const int y0  = qy * 4;

        const float* Ap = A + (size_t)c * HW1;
        const float* Bp = B + (size_t)c * HW1;

        // rowdiff(y,x) = d(y,x-1) - d(y,x+1), rows y0-1 .. y0+4
        float rd[6][4];
#pragma unroll
        for (int r = 0; r < 6; ++r) {
            const int yy = y0 - 1 + r;
            if (yy < 0 || yy >= HEI) {
                rd[r][0] = rd[r][1] = rd[r][2] = rd[r][3] = 0.f;
                continue;
            }
            const float* ap = Ap + (size_t)yy * WID;
            const float* bp = Bp + (size_t)yy * WID;
            const float4 a4 = *reinterpret_cast<const float4*>(ap + x0);
            const float4 b4 = *reinterpret_cast<const float4*>(bp + x0);
            const float dm = (qx > 0)   ? (ap[x0 - 1] - bp[x0 - 1]) : 0.f;
            const float dp = (qx < 255) ? (ap[x0 + 4] - bp[x0 + 4]) : 0.f;
            const float d0 = a4.x - b4.x;
            const float d1 = a4.y - b4.y;
            const float d2 = a4.z - b4.z;
            const float d3 = a4.w - b4.w;
            rd[r][0] = dm - d1;
            rd[r][1] = d0 - d2;
            rd[r][2] = d1 - d3;
            rd[r][3] = d2 - dp;
        }

        float s = 0.f;
#pragma unroll
        for (int o = 0; o < 4; ++o) {
#pragma unroll
            for (int i = 0; i < 4; ++i)
                s += fabsf(rd[o][i] + 2.f * rd[o + 1][i] + rd[o + 2][i]);
        }

        block_atomic_add(s, acc + 2, s1);
    }
}

// Spatial-consistency loss from pooled diff array P[24][256][256].
__global__ __launch_bounds__(256) void k_spa(const float* __restrict__ P,
                                             float* __restrict__ acc) {
    const int t = blockIdx.x * 256 + threadIdx.x;  // 0 .. 524287
    const int x = t & 255;
    const int y = (t >> 8) & 255;
    const int b = t >> 16;  // 0..7

    const float* Rr = P + (size_t)(b * 3 + 0) * 65536 + y * 256;
    const float* Gg = P + (size_t)(b * 3 + 1) * 65536 + y * 256;
    const float* Bb = P + (size_t)(b * 3 + 2) * 65536 + y * 256;

    const float g  = Gg[x];
    const float gl = (x > 0)   ? Gg[x - 1] : 0.f;
    const float gr = (x < 255) ? Gg[x + 1] : 0.f;
    const float d0 = g - gl;
    const float d1 = g - gr;
    const float d2 = g - Rr[x];
    const float d3 = g - Bb[x];
    float s = d0 * d0 + d1 * d1 + d2 * d2 + d3 * d3;

    __shared__ float sd[4];
    block_atomic_add(s, acc + 3, sd);
}

// Combine: out = W_C*c + W_R*r + W_P*p + W_S*s
__global__ void k_final(const float* __restrict__ acc, float* __restrict__ out) {
    const float r = acc[0] * (1.0f / 25165824.0f);  // mean over 8*3*1024*1024
    const float c = acc[1];
    const float s = acc[2];
    const float p = acc[3] * (1.0f / 524288.0f);    // mean over 8*256*256
    out[0] = 0.5f * c + 1.0f * r + 1.0f * p + 0.1f * s;
}

extern "C" void kernel_launch(void* const* d_in, const int* in_sizes, int n_in,
                              void* d_out, int out_size, void* d_ws, size_t ws_size,
                              hipStream_t stream) {
    const float* A = (const float*)d_in[0];  // predictions
    const float* B = (const float*)d_in[1];  // targets
    float* acc  = (float*)d_ws;              // 4 accumulators (+ padding)
    float* pool = (float*)d_ws + 64;         // 8*3*256*256 floats = 6.29 MB

    hipMemsetAsync(d_ws, 0, 64 * sizeof(float), stream);

    hipLaunchKernelGGL(k_fused, dim3(1792), dim3(256), 0, stream, A, B, pool, acc);
    hipLaunchKernelGGL(k_spa,   dim3(2048), dim3(256), 0, stream, pool, acc);
    hipLaunchKernelGGL(k_final, dim3(1),    dim3(1),   0, stream, acc, (float*)d_out);
}